// Round 1
// baseline (6031.635 us; speedup 1.0000x reference)
//
#include <hip/hip_runtime.h>
#include <hip/hip_bf16.h>
#include <hip/hip_fp16.h>

// ---------------- types ----------------
typedef __attribute__((ext_vector_type(8))) short bf16x8;   // 8 bf16 (4 VGPR)
typedef __attribute__((ext_vector_type(4))) float f32x4;    // MFMA acc

static __device__ __forceinline__ unsigned short f2bf(float f) {
  unsigned u = __float_as_uint(f);
  u += 0x7fffu + ((u >> 16) & 1u);   // RNE
  return (unsigned short)(u >> 16);
}
static __device__ __forceinline__ float bf2f(unsigned short h) {
  return __uint_as_float(((unsigned)h) << 16);
}
static __device__ __forceinline__ float sigm(float x) {
  return __builtin_amdgcn_rcpf(1.0f + __expf(-x));
}
static __device__ __forceinline__ float tanh_fast(float x) {
  return 2.0f * __builtin_amdgcn_rcpf(1.0f + __expf(-2.0f * x)) - 1.0f;
}
static __device__ __forceinline__ f32x4 splat4(float g) {
  f32x4 v; v[0] = g; v[1] = g; v[2] = g; v[3] = g; return v;
}

// ---------------- phase 0: weight transpose + bf16 convert ----------------
// wT layout: [set 2][n 768][k 320] bf16 ; n<512 -> gate cols, n>=512 -> cand cols
__global__ void prep_weights(const float* __restrict__ fw_gw, const float* __restrict__ fw_cw,
                             const float* __restrict__ bw_gw, const float* __restrict__ bw_cw,
                             unsigned short* __restrict__ wT) {
  int gid = blockIdx.x * 256 + threadIdx.x;   // 480*256 = 122880 threads, 4 elems each
  int kg = gid % 80;
  int n  = (gid / 80) % 768;
  int s  = gid / (80 * 768);
  if (s >= 2) return;
  const float* gw = s ? bw_gw : fw_gw;
  const float* cw = s ? bw_cw : fw_cw;
  unsigned short* dst = wT + ((size_t)s * 768 + n) * 320 + kg * 4;
  #pragma unroll
  for (int j = 0; j < 4; ++j) {
    int k = kg * 4 + j;
    float v = (n < 512) ? gw[(size_t)k * 512 + n] : cw[(size_t)k * 256 + (n - 512)];
    dst[j] = f2bf(v);
  }
}

// ---------------- phase 1: persistent dual-GRU ----------------
// grid 128: blockIdx>>6 = weight set (0 fw, 1 bw); &63 = batch row block (16 rows)
// m-tile 0 = target chain, m-tile 1 = probe chain (same weights) -> one weight stream, 32 rows
__global__ __launch_bounds__(512, 2) void gru_kernel(
    const float* __restrict__ seq,
    const float* __restrict__ fw_gb, const float* __restrict__ fw_cb,
    const float* __restrict__ bw_gb, const float* __restrict__ bw_cb,
    const unsigned short* __restrict__ wT,
    float* __restrict__ h_cat) {
  __shared__ unsigned short hA[32 * 256];    // bf16 h, XOR-swizzled
  __shared__ unsigned short rhA[32 * 256];   // bf16 r*h, XOR-swizzled
  __shared__ unsigned short uS[32 * 264];    // f16 u, padded stride

  const int tid  = threadIdx.x;
  const int wave = tid >> 6;
  const int lane = tid & 63;
  const int l15  = lane & 15;
  const int lk   = lane >> 4;
  const int ws   = blockIdx.x >> 6;
  const int rb   = blockIdx.x & 63;

  const unsigned short* wg = wT + (size_t)ws * (768 * 320);
  const unsigned short* wc = wg + (size_t)512 * 320;
  const float* gbp = ws ? bw_gb : fw_gb;
  const float* cbp = ws ? bw_cb : fw_cb;

  for (int i = tid; i < 32 * 256 / 2; i += 512) ((int*)hA)[i] = 0;

  const int n0g = wave * 64;   // GEMM1 col base (gates)
  const int n0c = wave * 32;   // GEMM2 col base (candidate)
  float gbias[4], cbias[2];
  #pragma unroll
  for (int nt = 0; nt < 4; ++nt) gbias[nt] = gbp[n0g + nt * 16 + l15];
  #pragma unroll
  for (int nt = 0; nt < 2; ++nt) cbias[nt] = cbp[n0c + nt * 16 + l15];

  const float* seqrow = seq + (size_t)(rb * 16 + l15) * (512 * 64);

  f32x4 hreg[2][2];  // persistent f32 h at this lane's GEMM2 C-frag positions
  #pragma unroll
  for (int a = 0; a < 2; ++a)
    #pragma unroll
    for (int b = 0; b < 2; ++b) hreg[a][b] = splat4(0.f);

  __syncthreads();

  for (int t = 0; t < 256; ++t) {
    const int tg0 = ws ? (255 - t) : t;          // target chain time
    const int tg1 = ws ? (511 - t) : (256 + t);  // probe chain time

    // ---- x A-fragments straight from global (L3-resident), reused by GEMM1+GEMM2 ----
    bf16x8 xf[2][2];
    #pragma unroll
    for (int kt = 0; kt < 2; ++kt) {
      const int kx = kt * 32 + lk * 8;
      const float* p0 = seqrow + tg0 * 64 + kx;
      const float* p1 = seqrow + tg1 * 64 + kx;
      float4 q0 = *(const float4*)p0;
      float4 q1 = *(const float4*)(p0 + 4);
      float4 q2 = *(const float4*)p1;
      float4 q3 = *(const float4*)(p1 + 4);
      bf16x8 v0, v1;
      v0[0] = (short)f2bf(q0.x); v0[1] = (short)f2bf(q0.y);
      v0[2] = (short)f2bf(q0.z); v0[3] = (short)f2bf(q0.w);
      v0[4] = (short)f2bf(q1.x); v0[5] = (short)f2bf(q1.y);
      v0[6] = (short)f2bf(q1.z); v0[7] = (short)f2bf(q1.w);
      v1[0] = (short)f2bf(q2.x); v1[1] = (short)f2bf(q2.y);
      v1[2] = (short)f2bf(q2.z); v1[3] = (short)f2bf(q2.w);
      v1[4] = (short)f2bf(q3.x); v1[5] = (short)f2bf(q3.y);
      v1[6] = (short)f2bf(q3.z); v1[7] = (short)f2bf(q3.w);
      xf[0][kt] = v0; xf[1][kt] = v1;
    }

    // ---- GEMM1: ru_pre = [x|h] @ gw + gb ; wave covers gate cols n0g..n0g+63 ----
    f32x4 acc1[2][4];
    #pragma unroll
    for (int mt = 0; mt < 2; ++mt)
      #pragma unroll
      for (int nt = 0; nt < 4; ++nt) acc1[mt][nt] = splat4(gbias[nt]);
    {
      bf16x8 bcur[4], bnxt[4];
      #pragma unroll
      for (int nt = 0; nt < 4; ++nt)
        bcur[nt] = *(const bf16x8*)(wg + (size_t)(n0g + nt * 16 + l15) * 320 + 64 + lk * 8);
      #pragma unroll
      for (int kk = 0; kk < 10; ++kk) {             // kk<8: h k-tiles (ktile kk+2); kk>=8: x tiles
        if (kk < 9) {
          const int koff = (kk < 7) ? ((kk + 3) * 32) : ((kk - 7) * 32);
          #pragma unroll
          for (int nt = 0; nt < 4; ++nt)
            bnxt[nt] = *(const bf16x8*)(wg + (size_t)(n0g + nt * 16 + l15) * 320 + koff + lk * 8);
        }
        bf16x8 a0, a1f;
        if (kk < 8) {
          int byte0 = (l15 * 512 + (kk * 32 + lk * 8) * 2) ^ ((l15 & 7) << 4);
          a0  = *(const bf16x8*)((const char*)hA + byte0);
          a1f = *(const bf16x8*)((const char*)hA + byte0 + 16 * 512);
        } else { a0 = xf[0][kk - 8]; a1f = xf[1][kk - 8]; }
        #pragma unroll
        for (int nt = 0; nt < 4; ++nt) {
          acc1[0][nt] = __builtin_amdgcn_mfma_f32_16x16x32_bf16(a0,  bcur[nt], acc1[0][nt], 0, 0, 0);
          acc1[1][nt] = __builtin_amdgcn_mfma_f32_16x16x32_bf16(a1f, bcur[nt], acc1[1][nt], 0, 0, 0);
        }
        #pragma unroll
        for (int nt = 0; nt < 4; ++nt) bcur[nt] = bnxt[nt];
      }
    }

    // ---- gate pointwise: waves 0-3 own r-cols -> write r*h ; waves 4-7 own u-cols ----
    if (wave < 4) {
      #pragma unroll
      for (int mt = 0; mt < 2; ++mt)
        #pragma unroll
        for (int nt = 0; nt < 4; ++nt)
          #pragma unroll
          for (int i = 0; i < 4; ++i) {
            const int row = mt * 16 + lk * 4 + i;
            const int col = n0g + nt * 16 + l15;          // 0..255
            const float r = sigm(acc1[mt][nt][i]);
            const int hb = (row * 512 + col * 2) ^ ((row & 7) << 4);
            const float hold = bf2f(*(const unsigned short*)((const char*)hA + hb));
            *(unsigned short*)((char*)rhA + hb) = f2bf(r * hold);
          }
    } else {
      #pragma unroll
      for (int mt = 0; mt < 2; ++mt)
        #pragma unroll
        for (int nt = 0; nt < 4; ++nt)
          #pragma unroll
          for (int i = 0; i < 4; ++i) {
            const int row = mt * 16 + lk * 4 + i;
            const int col = (n0g - 256) + nt * 16 + l15;  // 0..255
            uS[row * 264 + col] = __half_as_ushort(__float2half(sigm(acc1[mt][nt][i])));
          }
    }
    __syncthreads();

    // ---- GEMM2: c_pre = [x|r*h] @ cw + cb ; wave covers cand cols n0c..n0c+31 ----
    f32x4 acc2[2][2];
    #pragma unroll
    for (int mt = 0; mt < 2; ++mt)
      #pragma unroll
      for (int nt = 0; nt < 2; ++nt) acc2[mt][nt] = splat4(cbias[nt]);
    {
      bf16x8 bcur[2], bnxt[2];
      #pragma unroll
      for (int nt = 0; nt < 2; ++nt)
        bcur[nt] = *(const bf16x8*)(wc + (size_t)(n0c + nt * 16 + l15) * 320 + 64 + lk * 8);
      #pragma unroll
      for (int kk = 0; kk < 10; ++kk) {
        if (kk < 9) {
          const int koff = (kk < 7) ? ((kk + 3) * 32) : ((kk - 7) * 32);
          #pragma unroll
          for (int nt = 0; nt < 2; ++nt)
            bnxt[nt] = *(const bf16x8*)(wc + (size_t)(n0c + nt * 16 + l15) * 320 + koff + lk * 8);
        }
        bf16x8 a0, a1f;
        if (kk < 8) {
          int byte0 = (l15 * 512 + (kk * 32 + lk * 8) * 2) ^ ((l15 & 7) << 4);
          a0  = *(const bf16x8*)((const char*)rhA + byte0);
          a1f = *(const bf16x8*)((const char*)rhA + byte0 + 16 * 512);
        } else { a0 = xf[0][kk - 8]; a1f = xf[1][kk - 8]; }
        #pragma unroll
        for (int nt = 0; nt < 2; ++nt) {
          acc2[0][nt] = __builtin_amdgcn_mfma_f32_16x16x32_bf16(a0,  bcur[nt], acc2[0][nt], 0, 0, 0);
          acc2[1][nt] = __builtin_amdgcn_mfma_f32_16x16x32_bf16(a1f, bcur[nt], acc2[1][nt], 0, 0, 0);
        }
        #pragma unroll
        for (int nt = 0; nt < 2; ++nt) bcur[nt] = bnxt[nt];
      }
    }

    // ---- update: h = u*h + (1-u)*tanh(c_pre) ; h kept f32 in regs ----
    const bool last = (t == 255);
    #pragma unroll
    for (int mt = 0; mt < 2; ++mt)
      #pragma unroll
      for (int nt = 0; nt < 2; ++nt)
        #pragma unroll
        for (int i = 0; i < 4; ++i) {
          const int row = mt * 16 + lk * 4 + i;
          const int col = n0c + nt * 16 + l15;
          const float c = tanh_fast(acc2[mt][nt][i]);
          const float u = __half2float(__ushort_as_half(uS[row * 264 + col]));
          const float hn = u * hreg[mt][nt][i] + (1.f - u) * c;
          hreg[mt][nt][i] = hn;
          const int hb = (row * 512 + col * 2) ^ ((row & 7) << 4);
          *(unsigned short*)((char*)hA + hb) = f2bf(hn);
          if (last) {
            const int cat = (ws ? (mt ? 768 : 256) : (mt ? 512 : 0)) + col;
            h_cat[(size_t)(rb * 16 + lk * 4 + i) * 1024 + cat] = hn;
          }
        }
    __syncthreads();
  }
}

// ---------------- phase 2: MLP (all f32 for accuracy; cheap) ----------------
__global__ __launch_bounds__(256) void mlp1(const float* __restrict__ h_cat,
                                            const float* __restrict__ gf,
                                            const float* __restrict__ w1,
                                            const float* __restrict__ b1,
                                            float* __restrict__ a1) {
  __shared__ float xs[8][1036];
  const int tid = threadIdx.x;
  const int r0 = blockIdx.x * 8;
  for (int i = tid; i < 8 * 1032; i += 256) {
    int m = i / 1032, k = i - m * 1032;
    xs[m][k] = (k < 1024) ? h_cat[(size_t)(r0 + m) * 1024 + k]
                          : gf[(size_t)(r0 + m) * 8 + (k - 1024)];
  }
  __syncthreads();
  float acc0[8], acc1v[8];
  #pragma unroll
  for (int m = 0; m < 8; ++m) { acc0[m] = 0.f; acc1v[m] = 0.f; }
  const int n = tid;
  for (int k = 0; k < 1032; k += 4) {
    float wa[4], wb[4];
    #pragma unroll
    for (int j = 0; j < 4; ++j) {
      wa[j] = w1[(size_t)(k + j) * 512 + n];
      wb[j] = w1[(size_t)(k + j) * 512 + n + 256];
    }
    #pragma unroll
    for (int m = 0; m < 8; ++m) {
      float4 xv = *(const float4*)&xs[m][k];
      acc0[m]  = fmaf(xv.w, wa[3], fmaf(xv.z, wa[2], fmaf(xv.y, wa[1], fmaf(xv.x, wa[0], acc0[m]))));
      acc1v[m] = fmaf(xv.w, wb[3], fmaf(xv.z, wb[2], fmaf(xv.y, wb[1], fmaf(xv.x, wb[0], acc1v[m]))));
    }
  }
  const float bb0 = b1[n], bb1 = b1[n + 256];
  #pragma unroll
  for (int m = 0; m < 8; ++m) {
    a1[(size_t)(r0 + m) * 512 + n]       = fmaxf(acc0[m] + bb0, 0.f);
    a1[(size_t)(r0 + m) * 512 + n + 256] = fmaxf(acc1v[m] + bb1, 0.f);
  }
}

__global__ __launch_bounds__(256) void mlp2(const float* __restrict__ a1,
                                            const float* __restrict__ w2,
                                            const float* __restrict__ b2,
                                            float* __restrict__ a2) {
  __shared__ float xs[8][516];
  const int tid = threadIdx.x;
  const int r0 = blockIdx.x * 8;
  for (int i = tid; i < 8 * 512; i += 256) {
    int m = i >> 9, k = i & 511;
    xs[m][k] = a1[(size_t)(r0 + m) * 512 + k];
  }
  __syncthreads();
  float acc[8];
  #pragma unroll
  for (int m = 0; m < 8; ++m) acc[m] = 0.f;
  for (int k = 0; k < 512; k += 4) {
    float wa[4];
    #pragma unroll
    for (int j = 0; j < 4; ++j) wa[j] = w2[(size_t)(k + j) * 256 + tid];
    #pragma unroll
    for (int m = 0; m < 8; ++m) {
      float4 xv = *(const float4*)&xs[m][k];
      acc[m] = fmaf(xv.w, wa[3], fmaf(xv.z, wa[2], fmaf(xv.y, wa[1], fmaf(xv.x, wa[0], acc[m]))));
    }
  }
  const float bb = b2[tid];
  #pragma unroll
  for (int m = 0; m < 8; ++m)
    a2[(size_t)(r0 + m) * 256 + tid] = fmaxf(acc[m] + bb, 0.f);
}

__global__ __launch_bounds__(256) void mlp3(const float* __restrict__ a2,
                                            const float* __restrict__ w3,
                                            const float* __restrict__ b3,
                                            float* __restrict__ out) {
  const int r = blockIdx.x * 256 + threadIdx.x;
  float m = 0.f, p = 0.f;
  for (int k = 0; k < 256; k += 4) {
    float4 v = *(const float4*)&a2[(size_t)r * 256 + k];
    m = fmaf(v.x, w3[2 * k],     fmaf(v.y, w3[2 * k + 2], fmaf(v.z, w3[2 * k + 4], fmaf(v.w, w3[2 * k + 6], m))));
    p = fmaf(v.x, w3[2 * k + 1], fmaf(v.y, w3[2 * k + 3], fmaf(v.z, w3[2 * k + 5], fmaf(v.w, w3[2 * k + 7], p))));
  }
  out[2 * r]     = m + b3[0];
  out[2 * r + 1] = fabsf(p + b3[1]);
}

// ---------------- launch ----------------
extern "C" void kernel_launch(void* const* d_in, const int* in_sizes, int n_in,
                              void* d_out, int out_size, void* d_ws, size_t ws_size,
                              hipStream_t stream) {
  const float* seq   = (const float*)d_in[0];
  const float* gf    = (const float*)d_in[1];
  const float* fw_gw = (const float*)d_in[2];
  const float* fw_gb = (const float*)d_in[3];
  const float* fw_cw = (const float*)d_in[4];
  const float* fw_cb = (const float*)d_in[5];
  const float* bw_gw = (const float*)d_in[6];
  const float* bw_gb = (const float*)d_in[7];
  const float* bw_cw = (const float*)d_in[8];
  const float* bw_cb = (const float*)d_in[9];
  const float* w1 = (const float*)d_in[10];
  const float* b1 = (const float*)d_in[11];
  const float* w2 = (const float*)d_in[12];
  const float* b2 = (const float*)d_in[13];
  const float* w3 = (const float*)d_in[14];
  const float* b3 = (const float*)d_in[15];
  float* out = (float*)d_out;

  char* ws = (char*)d_ws;
  unsigned short* wT = (unsigned short*)(ws);                       // 983,040 B
  float* h_cat = (float*)(ws + 983040);                             // 4 MiB
  float* a1    = (float*)(ws + 983040 + 4194304);                   // 2 MiB
  float* a2    = (float*)(ws + 983040 + 4194304 + 2097152);         // 1 MiB

  hipLaunchKernelGGL(prep_weights, dim3(480), dim3(256), 0, stream,
                     fw_gw, fw_cw, bw_gw, bw_cw, wT);
  hipLaunchKernelGGL(gru_kernel, dim3(128), dim3(512), 0, stream,
                     seq, fw_gb, fw_cb, bw_gb, bw_cb, wT, h_cat);
  hipLaunchKernelGGL(mlp1, dim3(128), dim3(256), 0, stream, h_cat, gf, w1, b1, a1);
  hipLaunchKernelGGL(mlp2, dim3(128), dim3(256), 0, stream, a1, w2, b2, a2);
  hipLaunchKernelGGL(mlp3, dim3(4), dim3(256), 0, stream, a2, w3, b3, out);
}

// Round 2
// 1783.995 us; speedup vs baseline: 3.3810x; 3.3810x over previous
//
#include <hip/hip_runtime.h>
#include <hip/hip_bf16.h>
#include <hip/hip_fp16.h>

// ---------------- types ----------------
typedef __attribute__((ext_vector_type(8))) short bf16x8;   // 8 bf16 (4 VGPR)
typedef __attribute__((ext_vector_type(4))) float f32x4;    // MFMA acc

static __device__ __forceinline__ unsigned short f2bf(float f) {
  unsigned u = __float_as_uint(f);
  u += 0x7fffu + ((u >> 16) & 1u);   // RNE
  return (unsigned short)(u >> 16);
}
static __device__ __forceinline__ float bf2f(unsigned short h) {
  return __uint_as_float(((unsigned)h) << 16);
}
static __device__ __forceinline__ float sigm(float x) {
  return __builtin_amdgcn_rcpf(1.0f + __expf(-x));
}
static __device__ __forceinline__ float tanh_fast(float x) {
  return 2.0f * __builtin_amdgcn_rcpf(1.0f + __expf(-2.0f * x)) - 1.0f;
}
static __device__ __forceinline__ f32x4 splat4(float g) {
  f32x4 v; v[0] = g; v[1] = g; v[2] = g; v[3] = g; return v;
}

// ---------------- phase 0: weight transpose + bf16 convert ----------------
// wT layout: [set 2][n 768][k 320] bf16 ; n<512 -> gate cols, n>=512 -> cand cols
__global__ void prep_weights(const float* __restrict__ fw_gw, const float* __restrict__ fw_cw,
                             const float* __restrict__ bw_gw, const float* __restrict__ bw_cw,
                             unsigned short* __restrict__ wT) {
  int gid = blockIdx.x * 256 + threadIdx.x;   // 480*256 = 122880 threads, 4 elems each
  int kg = gid % 80;
  int n  = (gid / 80) % 768;
  int s  = gid / (80 * 768);
  if (s >= 2) return;
  const float* gw = s ? bw_gw : fw_gw;
  const float* cw = s ? bw_cw : fw_cw;
  unsigned short* dst = wT + ((size_t)s * 768 + n) * 320 + kg * 4;
  #pragma unroll
  for (int j = 0; j < 4; ++j) {
    int k = kg * 4 + j;
    float v = (n < 512) ? gw[(size_t)k * 512 + n] : cw[(size_t)k * 256 + (n - 512)];
    dst[j] = f2bf(v);
  }
}

// ---------------- phase 1: persistent dual-GRU, weights fully on-chip ----------------
// grid 256: ci = blockIdx>>6 in {0:tgt_fw, 1:tgt_bw, 2:prb_fw, 3:prb_bw}; rb = blockIdx&63.
// Each WG: 16 batch rows of ONE chain. Gate weights (64 cols/wave) live in VGPRs,
// candidate rh-part (256x256) lives in XOR-swizzled LDS, candidate x-part in VGPRs.
__global__ __launch_bounds__(512, 2) void gru_kernel(
    const float* __restrict__ seq,
    const float* __restrict__ fw_gb, const float* __restrict__ fw_cb,
    const float* __restrict__ bw_gb, const float* __restrict__ bw_cb,
    const unsigned short* __restrict__ wT,
    float* __restrict__ h_cat) {
  __shared__ unsigned short wcLDS[256 * 256];  // cand weights [col][k(rh)], XOR-swizzled: 131072 B
  __shared__ unsigned short hA[16 * 256];      // bf16 h, XOR-swizzled: 8192 B
  __shared__ unsigned short rhA[16 * 256];     // bf16 r*h, XOR-swizzled: 8192 B
  __shared__ unsigned short uS[16 * 264];      // f16 u, padded stride: 8448 B

  const int tid  = threadIdx.x;
  const int wave = tid >> 6;
  const int lane = tid & 63;
  const int l15  = lane & 15;
  const int lk   = lane >> 4;
  const int ci   = blockIdx.x >> 6;   // chain id
  const int rb   = blockIdx.x & 63;   // row block
  const int s    = ci & 1;            // weight set: 0 fw, 1 bw
  const int tbase = (ci >> 1) * 256;  // 0 target, 256 probe

  const unsigned short* wg = wT + (size_t)s * (768 * 320);
  const unsigned short* wc = wg + (size_t)512 * 320;
  const float* gbp = s ? bw_gb : fw_gb;
  const float* cbp = s ? bw_cb : fw_cb;

  // ---- one-time: stage cand rh-weights into swizzled LDS ----
  for (int i = tid; i < 256 * 32; i += 512) {
    int col = i >> 5;          // 0..255
    int ch  = i & 31;          // k chunk of 8 -> k = ch*8
    bf16x8 v = *(const bf16x8*)(wc + (size_t)col * 320 + 64 + ch * 8);
    int byte0 = (col * 512 + ch * 16) ^ ((col & 7) << 4);
    *(bf16x8*)((char*)wcLDS + byte0) = v;
  }
  // ---- one-time: zero h ----
  for (int i = tid; i < 16 * 256 / 2; i += 512) ((int*)hA)[i] = 0;

  const int n0g = wave * 64;   // GEMM1 gate col base
  const int n0c = wave * 32;   // GEMM2 cand col base

  // ---- one-time: gate weights + cand x-weights into registers ----
  bf16x8 wgr[4][10];
  #pragma unroll
  for (int nt = 0; nt < 4; ++nt) {
    const unsigned short* base = wg + (size_t)(n0g + nt * 16 + l15) * 320;
    #pragma unroll
    for (int kk = 0; kk < 10; ++kk) {
      const int k = (kk < 8) ? (64 + kk * 32) : ((kk - 8) * 32);
      wgr[nt][kk] = *(const bf16x8*)(base + k + lk * 8);
    }
  }
  bf16x8 wcx[2][2];
  #pragma unroll
  for (int nt = 0; nt < 2; ++nt) {
    const unsigned short* base = wc + (size_t)(n0c + nt * 16 + l15) * 320;
    #pragma unroll
    for (int kt = 0; kt < 2; ++kt)
      wcx[nt][kt] = *(const bf16x8*)(base + kt * 32 + lk * 8);
  }

  float gbias[4], cbias[2];
  #pragma unroll
  for (int nt = 0; nt < 4; ++nt) gbias[nt] = gbp[n0g + nt * 16 + l15];
  #pragma unroll
  for (int nt = 0; nt < 2; ++nt) cbias[nt] = cbp[n0c + nt * 16 + l15];

  const float* seqrow = seq + (size_t)(rb * 16 + l15) * (512 * 64);

  f32x4 hreg[2];   // persistent f32 h at this lane's GEMM2 C-frag positions
  hreg[0] = splat4(0.f); hreg[1] = splat4(0.f);

  __syncthreads();

  #pragma unroll 1
  for (int t = 0; t < 256; ++t) {
    const int tg = tbase + (s ? (255 - t) : t);

    // ---- x A-fragment straight from global (L3-resident), reused by GEMM1+GEMM2 ----
    bf16x8 xf[2];
    #pragma unroll
    for (int kt = 0; kt < 2; ++kt) {
      const float* p0 = seqrow + (size_t)tg * 64 + kt * 32 + lk * 8;
      float4 q0 = *(const float4*)p0;
      float4 q1 = *(const float4*)(p0 + 4);
      bf16x8 v0;
      v0[0] = (short)f2bf(q0.x); v0[1] = (short)f2bf(q0.y);
      v0[2] = (short)f2bf(q0.z); v0[3] = (short)f2bf(q0.w);
      v0[4] = (short)f2bf(q1.x); v0[5] = (short)f2bf(q1.y);
      v0[6] = (short)f2bf(q1.z); v0[7] = (short)f2bf(q1.w);
      xf[kt] = v0;
    }

    // ---- GEMM1: ru_pre = [h|x] @ gw + gb ; wave covers gate cols n0g..n0g+63 ----
    f32x4 acc1[4];
    #pragma unroll
    for (int nt = 0; nt < 4; ++nt) acc1[nt] = splat4(gbias[nt]);
    #pragma unroll
    for (int kk = 0; kk < 10; ++kk) {
      bf16x8 a0;
      if (kk < 8) {
        const int byte0 = (l15 * 512 + (kk * 32 + lk * 8) * 2) ^ ((l15 & 7) << 4);
        a0 = *(const bf16x8*)((const char*)hA + byte0);
      } else {
        a0 = xf[kk - 8];
      }
      #pragma unroll
      for (int nt = 0; nt < 4; ++nt)
        acc1[nt] = __builtin_amdgcn_mfma_f32_16x16x32_bf16(a0, wgr[nt][kk], acc1[nt], 0, 0, 0);
    }

    // ---- gate pointwise: waves 0-3 own r-cols -> write r*h ; waves 4-7 own u-cols ----
    if (wave < 4) {
      #pragma unroll
      for (int nt = 0; nt < 4; ++nt)
        #pragma unroll
        for (int i = 0; i < 4; ++i) {
          const int row = lk * 4 + i;
          const int col = n0g + nt * 16 + l15;          // 0..255 (r cols)
          const float r = sigm(acc1[nt][i]);
          const int hb = (row * 512 + col * 2) ^ ((row & 7) << 4);
          const float hold = bf2f(*(const unsigned short*)((const char*)hA + hb));
          *(unsigned short*)((char*)rhA + hb) = f2bf(r * hold);
        }
    } else {
      #pragma unroll
      for (int nt = 0; nt < 4; ++nt)
        #pragma unroll
        for (int i = 0; i < 4; ++i) {
          const int row = lk * 4 + i;
          const int col = (n0g - 256) + nt * 16 + l15;  // 0..255 (u cols)
          uS[row * 264 + col] = __half_as_ushort(__float2half(sigm(acc1[nt][i])));
        }
    }
    __syncthreads();

    // ---- GEMM2: c_pre = [rh|x] @ cw + cb ; wave covers cand cols n0c..n0c+31 ----
    f32x4 acc2[2];
    #pragma unroll
    for (int nt = 0; nt < 2; ++nt) acc2[nt] = splat4(cbias[nt]);
    #pragma unroll
    for (int kk = 0; kk < 10; ++kk) {
      bf16x8 a0;
      if (kk < 8) {
        const int byte0 = (l15 * 512 + (kk * 32 + lk * 8) * 2) ^ ((l15 & 7) << 4);
        a0 = *(const bf16x8*)((const char*)rhA + byte0);
      } else {
        a0 = xf[kk - 8];
      }
      #pragma unroll
      for (int nt = 0; nt < 2; ++nt) {
        bf16x8 b;
        if (kk < 8) {
          const int col = n0c + nt * 16 + l15;
          const int bb = (col * 512 + (kk * 32 + lk * 8) * 2) ^ ((col & 7) << 4);
          b = *(const bf16x8*)((const char*)wcLDS + bb);
        } else {
          b = wcx[nt][kk - 8];
        }
        acc2[nt] = __builtin_amdgcn_mfma_f32_16x16x32_bf16(a0, b, acc2[nt], 0, 0, 0);
      }
    }

    // ---- update: h = u*h + (1-u)*tanh(c_pre) ; h kept f32 in regs ----
    const bool last = (t == 255);
    #pragma unroll
    for (int nt = 0; nt < 2; ++nt)
      #pragma unroll
      for (int i = 0; i < 4; ++i) {
        const int row = lk * 4 + i;
        const int col = n0c + nt * 16 + l15;
        const float cv = tanh_fast(acc2[nt][i]);
        const float u = __half2float(__ushort_as_half(uS[row * 264 + col]));
        const float hn = u * hreg[nt][i] + (1.f - u) * cv;
        hreg[nt][i] = hn;
        const int hb = (row * 512 + col * 2) ^ ((row & 7) << 4);
        *(unsigned short*)((char*)hA + hb) = f2bf(hn);
        if (last) {
          h_cat[(size_t)(rb * 16 + row) * 1024 + ci * 256 + col] = hn;
        }
      }
    __syncthreads();
  }
}

// ---------------- phase 2: MLP (all f32 for accuracy; cheap) ----------------
__global__ __launch_bounds__(256) void mlp1(const float* __restrict__ h_cat,
                                            const float* __restrict__ gf,
                                            const float* __restrict__ w1,
                                            const float* __restrict__ b1,
                                            float* __restrict__ a1) {
  __shared__ float xs[8][1036];
  const int tid = threadIdx.x;
  const int r0 = blockIdx.x * 8;
  for (int i = tid; i < 8 * 1032; i += 256) {
    int m = i / 1032, k = i - m * 1032;
    xs[m][k] = (k < 1024) ? h_cat[(size_t)(r0 + m) * 1024 + k]
                          : gf[(size_t)(r0 + m) * 8 + (k - 1024)];
  }
  __syncthreads();
  float acc0[8], acc1v[8];
  #pragma unroll
  for (int m = 0; m < 8; ++m) { acc0[m] = 0.f; acc1v[m] = 0.f; }
  const int n = tid;
  for (int k = 0; k < 1032; k += 4) {
    float wa[4], wb[4];
    #pragma unroll
    for (int j = 0; j < 4; ++j) {
      wa[j] = w1[(size_t)(k + j) * 512 + n];
      wb[j] = w1[(size_t)(k + j) * 512 + n + 256];
    }
    #pragma unroll
    for (int m = 0; m < 8; ++m) {
      float4 xv = *(const float4*)&xs[m][k];
      acc0[m]  = fmaf(xv.w, wa[3], fmaf(xv.z, wa[2], fmaf(xv.y, wa[1], fmaf(xv.x, wa[0], acc0[m]))));
      acc1v[m] = fmaf(xv.w, wb[3], fmaf(xv.z, wb[2], fmaf(xv.y, wb[1], fmaf(xv.x, wb[0], acc1v[m]))));
    }
  }
  const float bb0 = b1[n], bb1 = b1[n + 256];
  #pragma unroll
  for (int m = 0; m < 8; ++m) {
    a1[(size_t)(r0 + m) * 512 + n]       = fmaxf(acc0[m] + bb0, 0.f);
    a1[(size_t)(r0 + m) * 512 + n + 256] = fmaxf(acc1v[m] + bb1, 0.f);
  }
}

__global__ __launch_bounds__(256) void mlp2(const float* __restrict__ a1,
                                            const float* __restrict__ w2,
                                            const float* __restrict__ b2,
                                            float* __restrict__ a2) {
  __shared__ float xs[8][516];
  const int tid = threadIdx.x;
  const int r0 = blockIdx.x * 8;
  for (int i = tid; i < 8 * 512; i += 256) {
    int m = i >> 9, k = i & 511;
    xs[m][k] = a1[(size_t)(r0 + m) * 512 + k];
  }
  __syncthreads();
  float acc[8];
  #pragma unroll
  for (int m = 0; m < 8; ++m) acc[m] = 0.f;
  for (int k = 0; k < 512; k += 4) {
    float wa[4];
    #pragma unroll
    for (int j = 0; j < 4; ++j) wa[j] = w2[(size_t)(k + j) * 256 + tid];
    #pragma unroll
    for (int m = 0; m < 8; ++m) {
      float4 xv = *(const float4*)&xs[m][k];
      acc[m] = fmaf(xv.w, wa[3], fmaf(xv.z, wa[2], fmaf(xv.y, wa[1], fmaf(xv.x, wa[0], acc[m]))));
    }
  }
  const float bb = b2[tid];
  #pragma unroll
  for (int m = 0; m < 8; ++m)
    a2[(size_t)(r0 + m) * 256 + tid] = fmaxf(acc[m] + bb, 0.f);
}

__global__ __launch_bounds__(256) void mlp3(const float* __restrict__ a2,
                                            const float* __restrict__ w3,
                                            const float* __restrict__ b3,
                                            float* __restrict__ out) {
  const int r = blockIdx.x * 256 + threadIdx.x;
  float m = 0.f, p = 0.f;
  for (int k = 0; k < 256; k += 4) {
    float4 v = *(const float4*)&a2[(size_t)r * 256 + k];
    m = fmaf(v.x, w3[2 * k],     fmaf(v.y, w3[2 * k + 2], fmaf(v.z, w3[2 * k + 4], fmaf(v.w, w3[2 * k + 6], m))));
    p = fmaf(v.x, w3[2 * k + 1], fmaf(v.y, w3[2 * k + 3], fmaf(v.z, w3[2 * k + 5], fmaf(v.w, w3[2 * k + 7], p))));
  }
  out[2 * r]     = m + b3[0];
  out[2 * r + 1] = fabsf(p + b3[1]);
}

// ---------------- launch ----------------
extern "C" void kernel_launch(void* const* d_in, const int* in_sizes, int n_in,
                              void* d_out, int out_size, void* d_ws, size_t ws_size,
                              hipStream_t stream) {
  const float* seq   = (const float*)d_in[0];
  const float* gf    = (const float*)d_in[1];
  const float* fw_gw = (const float*)d_in[2];
  const float* fw_gb = (const float*)d_in[3];
  const float* fw_cw = (const float*)d_in[4];
  const float* fw_cb = (const float*)d_in[5];
  const float* bw_gw = (const float*)d_in[6];
  const float* bw_gb = (const float*)d_in[7];
  const float* bw_cw = (const float*)d_in[8];
  const float* bw_cb = (const float*)d_in[9];
  const float* w1 = (const float*)d_in[10];
  const float* b1 = (const float*)d_in[11];
  const float* w2 = (const float*)d_in[12];
  const float* b2 = (const float*)d_in[13];
  const float* w3 = (const float*)d_in[14];
  const float* b3 = (const float*)d_in[15];
  float* out = (float*)d_out;

  char* ws = (char*)d_ws;
  unsigned short* wT = (unsigned short*)(ws);                       // 983,040 B
  float* h_cat = (float*)(ws + 983040);                             // 4 MiB
  float* a1    = (float*)(ws + 983040 + 4194304);                   // 2 MiB
  float* a2    = (float*)(ws + 983040 + 4194304 + 2097152);         // 1 MiB

  hipLaunchKernelGGL(prep_weights, dim3(480), dim3(256), 0, stream,
                     fw_gw, fw_cw, bw_gw, bw_cw, wT);
  hipLaunchKernelGGL(gru_kernel, dim3(256), dim3(512), 0, stream,
                     seq, fw_gb, fw_cb, bw_gb, bw_cb, wT, h_cat);
  hipLaunchKernelGGL(mlp1, dim3(128), dim3(256), 0, stream, h_cat, gf, w1, b1, a1);
  hipLaunchKernelGGL(mlp2, dim3(128), dim3(256), 0, stream, a1, w2, b2, a2);
  hipLaunchKernelGGL(mlp3, dim3(4), dim3(256), 0, stream, a2, w3, b3, out);
}

// Round 3
// 1272.700 us; speedup vs baseline: 4.7392x; 1.4017x over previous
//
#include <hip/hip_runtime.h>
#include <hip/hip_bf16.h>
#include <hip/hip_fp16.h>

// ---------------- types ----------------
typedef __attribute__((ext_vector_type(8))) short bf16x8;   // 8 bf16 (4 VGPR)
typedef __attribute__((ext_vector_type(4))) float f32x4;    // MFMA acc

static __device__ __forceinline__ unsigned short f2bf(float f) {
  unsigned u = __float_as_uint(f);
  u += 0x7fffu + ((u >> 16) & 1u);   // RNE
  return (unsigned short)(u >> 16);
}
static __device__ __forceinline__ float bf2f(unsigned short h) {
  return __uint_as_float(((unsigned)h) << 16);
}
static __device__ __forceinline__ float sigm(float x) {
  return __builtin_amdgcn_rcpf(1.0f + __expf(-x));
}
static __device__ __forceinline__ float tanh_fast(float x) {
  return 2.0f * __builtin_amdgcn_rcpf(1.0f + __expf(-2.0f * x)) - 1.0f;
}
static __device__ __forceinline__ f32x4 splat4(float g) {
  f32x4 v; v[0] = g; v[1] = g; v[2] = g; v[3] = g; return v;
}

// ---------------- phase 0: weight transpose + bf16 convert ----------------
// wT layout: [set 2][n 768][k 320] bf16 ; n<512 -> gate cols (r:0-255,u:256-511), n>=512 -> cand cols
__global__ void prep_weights(const float* __restrict__ fw_gw, const float* __restrict__ fw_cw,
                             const float* __restrict__ bw_gw, const float* __restrict__ bw_cw,
                             unsigned short* __restrict__ wT) {
  int gid = blockIdx.x * 256 + threadIdx.x;   // 480*256 = 122880 threads, 4 elems each
  int kg = gid % 80;
  int n  = (gid / 80) % 768;
  int s  = gid / (80 * 768);
  if (s >= 2) return;
  const float* gw = s ? bw_gw : fw_gw;
  const float* cw = s ? bw_cw : fw_cw;
  unsigned short* dst = wT + ((size_t)s * 768 + n) * 320 + kg * 4;
  #pragma unroll
  for (int j = 0; j < 4; ++j) {
    int k = kg * 4 + j;
    float v = (n < 512) ? gw[(size_t)k * 512 + n] : cw[(size_t)k * 256 + (n - 512)];
    dst[j] = f2bf(v);
  }
}

// ---------------- phase 1: persistent dual-GRU, weights on-chip ----------------
// grid 256: ci = blockIdx>>6 in {0:tgt_fw, 1:tgt_bw, 2:prb_fw, 3:prb_bw}; rb = blockIdx&63.
// 16 batch rows per WG. Gate weights in VGPRs (wave w owns r-cols w*32..+31 and
// u-cols 256+w*32..+31 so u_pre stays in registers). Cand rh-weights in LDS
// (conflict-free linear tile layout), cand x-weights in VGPRs.
__global__ __launch_bounds__(512, 1) void gru_kernel(
    const float* __restrict__ seq,
    const float* __restrict__ fw_gb, const float* __restrict__ fw_cb,
    const float* __restrict__ bw_gb, const float* __restrict__ bw_cb,
    const unsigned short* __restrict__ wT,
    float* __restrict__ h_cat) {
  __shared__ unsigned short wcLDS[256 * 256];  // cand rh-weights, linear-tile frags: 131072 B
  __shared__ unsigned short hA[16 * 256];      // bf16 h, XOR-swizzled: 8192 B
  __shared__ unsigned short rhA[16 * 256];     // bf16 r*h, XOR-swizzled: 8192 B

  const int tid  = threadIdx.x;
  const int wave = tid >> 6;
  const int lane = tid & 63;
  const int l15  = lane & 15;
  const int lk   = lane >> 4;
  const int ci   = blockIdx.x >> 6;   // chain id
  const int rb   = blockIdx.x & 63;   // row block
  const int s    = ci & 1;            // weight set: 0 fw, 1 bw
  const int tbase = (ci >> 1) * 256;  // 0 target, 256 probe

  const unsigned short* wg = wT + (size_t)s * (768 * 320);
  const unsigned short* wc = wg + (size_t)512 * 320;
  const float* gbp = s ? bw_gb : fw_gb;
  const float* cbp = s ? bw_cb : fw_cb;

  // ---- one-time: stage cand rh-weights into LDS, linear B-fragment layout ----
  // element (col = c16*16 + l15, k = 64 + kk*32 + lk*8 ..+8) stored at byte
  // (((c16*8 + kk)*4 + lk)*16 + l15)*16  -> wave reads are contiguous 1KB.
  for (int i = tid; i < 8192; i += 512) {
    const int l15s = i & 15, lks = (i >> 4) & 3, kks = (i >> 6) & 7, c16 = i >> 9;
    bf16x8 v = *(const bf16x8*)(wc + (size_t)(c16 * 16 + l15s) * 320 + 64 + kks * 32 + lks * 8);
    *(bf16x8*)((char*)wcLDS + (size_t)i * 16) = v;
  }
  // ---- one-time: zero h ----
  for (int i = tid; i < 2048; i += 512) ((int*)hA)[i] = 0;

  const int n0c = wave * 32;   // GEMM2 cand col base (also h-col base for this wave)
  // GEMM1 gate col bases: nt 0,1 -> r cols ; nt 2,3 -> u cols for the same h-cols
  int colb[4];
  colb[0] = wave * 32;       colb[1] = wave * 32 + 16;
  colb[2] = 256 + wave * 32; colb[3] = 256 + wave * 32 + 16;

  // ---- one-time: gate weights + cand x-weights into registers ----
  bf16x8 wgr[4][10];
  #pragma unroll
  for (int nt = 0; nt < 4; ++nt) {
    const unsigned short* base = wg + (size_t)(colb[nt] + l15) * 320;
    #pragma unroll
    for (int kk = 0; kk < 10; ++kk) {
      const int k = (kk < 8) ? (64 + kk * 32) : ((kk - 8) * 32);
      wgr[nt][kk] = *(const bf16x8*)(base + k + lk * 8);
    }
  }
  bf16x8 wcx[2][2];
  #pragma unroll
  for (int nt = 0; nt < 2; ++nt) {
    const unsigned short* base = wc + (size_t)(n0c + nt * 16 + l15) * 320;
    #pragma unroll
    for (int kt = 0; kt < 2; ++kt)
      wcx[nt][kt] = *(const bf16x8*)(base + kt * 32 + lk * 8);
  }

  float gbias[4], cbias[2];
  #pragma unroll
  for (int nt = 0; nt < 4; ++nt) gbias[nt] = gbp[colb[nt] + l15];
  #pragma unroll
  for (int nt = 0; nt < 2; ++nt) cbias[nt] = cbp[n0c + nt * 16 + l15];

  const float* seqrow = seq + (size_t)(rb * 16 + l15) * (512 * 64);

  f32x4 hreg[2];   // persistent f32 h at this lane's GEMM2 C-frag positions
  hreg[0] = splat4(0.f); hreg[1] = splat4(0.f);

  __syncthreads();

  #pragma unroll 1
  for (int t = 0; t < 256; ++t) {
    const int tg = tbase + (s ? (255 - t) : t);

    // ---- x A-fragment straight from global (L3-resident), reused by GEMM1+GEMM2 ----
    bf16x8 xf[2];
    #pragma unroll
    for (int kt = 0; kt < 2; ++kt) {
      const float* p0 = seqrow + (size_t)tg * 64 + kt * 32 + lk * 8;
      float4 q0 = *(const float4*)p0;
      float4 q1 = *(const float4*)(p0 + 4);
      bf16x8 v0;
      v0[0] = (short)f2bf(q0.x); v0[1] = (short)f2bf(q0.y);
      v0[2] = (short)f2bf(q0.z); v0[3] = (short)f2bf(q0.w);
      v0[4] = (short)f2bf(q1.x); v0[5] = (short)f2bf(q1.y);
      v0[6] = (short)f2bf(q1.z); v0[7] = (short)f2bf(q1.w);
      xf[kt] = v0;
    }

    // ---- GEMM1: ru_pre = [h|x] @ gw + gb ----
    f32x4 acc1[4];
    #pragma unroll
    for (int nt = 0; nt < 4; ++nt) acc1[nt] = splat4(gbias[nt]);
    #pragma unroll
    for (int kk = 0; kk < 10; ++kk) {
      bf16x8 a0;
      if (kk < 8) {
        const int byte0 = (l15 * 512 + (kk * 32 + lk * 8) * 2) ^ ((l15 & 7) << 4);
        a0 = *(const bf16x8*)((const char*)hA + byte0);
      } else {
        a0 = xf[kk - 8];
      }
      #pragma unroll
      for (int nt = 0; nt < 4; ++nt)
        acc1[nt] = __builtin_amdgcn_mfma_f32_16x16x32_bf16(a0, wgr[nt][kk], acc1[nt], 0, 0, 0);
    }

    // ---- pointwise: r -> rhA (LDS) ; u -> registers (aligned with acc2 frags) ----
    float ur[2][4];
    #pragma unroll
    for (int nt = 0; nt < 2; ++nt)
      #pragma unroll
      for (int i = 0; i < 4; ++i) {
        const int row = lk * 4 + i;
        const int col = colb[nt] + l15;               // r col (= h col)
        const float r = sigm(acc1[nt][i]);
        const int hb = (row * 512 + col * 2) ^ ((row & 7) << 4);
        const float hold = bf2f(*(const unsigned short*)((const char*)hA + hb));
        *(unsigned short*)((char*)rhA + hb) = f2bf(r * hold);
        ur[nt][i] = sigm(acc1[nt + 2][i]);            // u for same (row,col)
      }
    __syncthreads();

    // ---- GEMM2: c_pre = [rh|x] @ cw + cb ----
    f32x4 acc2[2];
    #pragma unroll
    for (int nt = 0; nt < 2; ++nt) acc2[nt] = splat4(cbias[nt]);
    #pragma unroll
    for (int kk = 0; kk < 10; ++kk) {
      bf16x8 a0;
      if (kk < 8) {
        const int byte0 = (l15 * 512 + (kk * 32 + lk * 8) * 2) ^ ((l15 & 7) << 4);
        a0 = *(const bf16x8*)((const char*)rhA + byte0);
      } else {
        a0 = xf[kk - 8];
      }
      #pragma unroll
      for (int nt = 0; nt < 2; ++nt) {
        bf16x8 b;
        if (kk < 8) {
          const int c16 = wave * 2 + nt;
          b = *(const bf16x8*)((const char*)wcLDS +
                (size_t)((((c16 * 8 + kk) * 4 + lk) * 16 + l15) * 16));
        } else {
          b = wcx[nt][kk - 8];
        }
        acc2[nt] = __builtin_amdgcn_mfma_f32_16x16x32_bf16(a0, b, acc2[nt], 0, 0, 0);
      }
    }

    // ---- update: h = u*h + (1-u)*tanh(c_pre) ; h kept f32 in regs ----
    const bool last = (t == 255);
    #pragma unroll
    for (int nt = 0; nt < 2; ++nt)
      #pragma unroll
      for (int i = 0; i < 4; ++i) {
        const int row = lk * 4 + i;
        const int col = n0c + nt * 16 + l15;
        const float cv = tanh_fast(acc2[nt][i]);
        const float u = ur[nt][i];
        const float hn = u * hreg[nt][i] + (1.f - u) * cv;
        hreg[nt][i] = hn;
        const int hb = (row * 512 + col * 2) ^ ((row & 7) << 4);
        *(unsigned short*)((char*)hA + hb) = f2bf(hn);
        if (last) {
          h_cat[(size_t)(rb * 16 + row) * 1024 + ci * 256 + col] = hn;
        }
      }
    __syncthreads();
  }
}

// ---------------- phase 2: MLP (all f32 for accuracy; cheap) ----------------
__global__ __launch_bounds__(256) void mlp1(const float* __restrict__ h_cat,
                                            const float* __restrict__ gf,
                                            const float* __restrict__ w1,
                                            const float* __restrict__ b1,
                                            float* __restrict__ a1) {
  __shared__ float xs[8][1036];
  const int tid = threadIdx.x;
  const int r0 = blockIdx.x * 8;
  for (int i = tid; i < 8 * 1032; i += 256) {
    int m = i / 1032, k = i - m * 1032;
    xs[m][k] = (k < 1024) ? h_cat[(size_t)(r0 + m) * 1024 + k]
                          : gf[(size_t)(r0 + m) * 8 + (k - 1024)];
  }
  __syncthreads();
  float acc0[8], acc1v[8];
  #pragma unroll
  for (int m = 0; m < 8; ++m) { acc0[m] = 0.f; acc1v[m] = 0.f; }
  const int n = tid;
  for (int k = 0; k < 1032; k += 4) {
    float wa[4], wb[4];
    #pragma unroll
    for (int j = 0; j < 4; ++j) {
      wa[j] = w1[(size_t)(k + j) * 512 + n];
      wb[j] = w1[(size_t)(k + j) * 512 + n + 256];
    }
    #pragma unroll
    for (int m = 0; m < 8; ++m) {
      float4 xv = *(const float4*)&xs[m][k];
      acc0[m]  = fmaf(xv.w, wa[3], fmaf(xv.z, wa[2], fmaf(xv.y, wa[1], fmaf(xv.x, wa[0], acc0[m]))));
      acc1v[m] = fmaf(xv.w, wb[3], fmaf(xv.z, wb[2], fmaf(xv.y, wb[1], fmaf(xv.x, wb[0], acc1v[m]))));
    }
  }
  const float bb0 = b1[n], bb1 = b1[n + 256];
  #pragma unroll
  for (int m = 0; m < 8; ++m) {
    a1[(size_t)(r0 + m) * 512 + n]       = fmaxf(acc0[m] + bb0, 0.f);
    a1[(size_t)(r0 + m) * 512 + n + 256] = fmaxf(acc1v[m] + bb1, 0.f);
  }
}

__global__ __launch_bounds__(256) void mlp2(const float* __restrict__ a1,
                                            const float* __restrict__ w2,
                                            const float* __restrict__ b2,
                                            float* __restrict__ a2) {
  __shared__ float xs[8][516];
  const int tid = threadIdx.x;
  const int r0 = blockIdx.x * 8;
  for (int i = tid; i < 8 * 512; i += 256) {
    int m = i >> 9, k = i & 511;
    xs[m][k] = a1[(size_t)(r0 + m) * 512 + k];
  }
  __syncthreads();
  float acc[8];
  #pragma unroll
  for (int m = 0; m < 8; ++m) acc[m] = 0.f;
  for (int k = 0; k < 512; k += 4) {
    float wa[4];
    #pragma unroll
    for (int j = 0; j < 4; ++j) wa[j] = w2[(size_t)(k + j) * 256 + tid];
    #pragma unroll
    for (int m = 0; m < 8; ++m) {
      float4 xv = *(const float4*)&xs[m][k];
      acc[m] = fmaf(xv.w, wa[3], fmaf(xv.z, wa[2], fmaf(xv.y, wa[1], fmaf(xv.x, wa[0], acc[m]))));
    }
  }
  const float bb = b2[tid];
  #pragma unroll
  for (int m = 0; m < 8; ++m)
    a2[(size_t)(r0 + m) * 256 + tid] = fmaxf(acc[m] + bb, 0.f);
}

__global__ __launch_bounds__(256) void mlp3(const float* __restrict__ a2,
                                            const float* __restrict__ w3,
                                            const float* __restrict__ b3,
                                            float* __restrict__ out) {
  const int r = blockIdx.x * 256 + threadIdx.x;
  float m = 0.f, p = 0.f;
  for (int k = 0; k < 256; k += 4) {
    float4 v = *(const float4*)&a2[(size_t)r * 256 + k];
    m = fmaf(v.x, w3[2 * k],     fmaf(v.y, w3[2 * k + 2], fmaf(v.z, w3[2 * k + 4], fmaf(v.w, w3[2 * k + 6], m))));
    p = fmaf(v.x, w3[2 * k + 1], fmaf(v.y, w3[2 * k + 3], fmaf(v.z, w3[2 * k + 5], fmaf(v.w, w3[2 * k + 7], p))));
  }
  out[2 * r]     = m + b3[0];
  out[2 * r + 1] = fabsf(p + b3[1]);
}

// ---------------- launch ----------------
extern "C" void kernel_launch(void* const* d_in, const int* in_sizes, int n_in,
                              void* d_out, int out_size, void* d_ws, size_t ws_size,
                              hipStream_t stream) {
  const float* seq   = (const float*)d_in[0];
  const float* gf    = (const float*)d_in[1];
  const float* fw_gw = (const float*)d_in[2];
  const float* fw_gb = (const float*)d_in[3];
  const float* fw_cw = (const float*)d_in[4];
  const float* fw_cb = (const float*)d_in[5];
  const float* bw_gw = (const float*)d_in[6];
  const float* bw_gb = (const float*)d_in[7];
  const float* bw_cw = (const float*)d_in[8];
  const float* bw_cb = (const float*)d_in[9];
  const float* w1 = (const float*)d_in[10];
  const float* b1 = (const float*)d_in[11];
  const float* w2 = (const float*)d_in[12];
  const float* b2 = (const float*)d_in[13];
  const float* w3 = (const float*)d_in[14];
  const float* b3 = (const float*)d_in[15];
  float* out = (float*)d_out;

  char* ws = (char*)d_ws;
  unsigned short* wT = (unsigned short*)(ws);                       // 983,040 B
  float* h_cat = (float*)(ws + 983040);                             // 4 MiB
  float* a1    = (float*)(ws + 983040 + 4194304);                   // 2 MiB
  float* a2    = (float*)(ws + 983040 + 4194304 + 2097152);         // 1 MiB

  hipLaunchKernelGGL(prep_weights, dim3(480), dim3(256), 0, stream,
                     fw_gw, fw_cw, bw_gw, bw_cw, wT);
  hipLaunchKernelGGL(gru_kernel, dim3(256), dim3(512), 0, stream,
                     seq, fw_gb, fw_cb, bw_gb, bw_cb, wT, h_cat);
  hipLaunchKernelGGL(mlp1, dim3(128), dim3(256), 0, stream, h_cat, gf, w1, b1, a1);
  hipLaunchKernelGGL(mlp2, dim3(128), dim3(256), 0, stream, a1, w2, b2, a2);
  hipLaunchKernelGGL(mlp3, dim3(4), dim3(256), 0, stream, a2, w3, b3, out);
}